// Round 8
// baseline (285.671 us; speedup 1.0000x reference)
//
#include <hip/hip_runtime.h>
#include <hip/hip_bf16.h>
#include <stdint.h>

// RBF kernel matrix: out[n,m] = exp(2*x.(g*y) - sqx[n] - sqy[m])
// Pre-pass converts x and w=2*g*y to split-bf16 (hi/lo) once, in MFMA fragment
// order in d_ws; main kernel: frag loads -> MFMAs -> exp -> per-wave LDS
// transpose -> nontemporal float4 stores (barrier-free epilogue, as R7).
// R8: tile 64x64 -> 128x128 (wave = 32x128 slab). Per-block L2 reads drop
// from 80KB/16KB-out (5:1) to 160KB/64KB-out (2.5:1): total L2 read traffic
// 1.31 GB -> 655 MB. Theory: per-XCD L2 R+W was ~77% of its ~4.3 TB/s
// ceiling, throttling the store stream (occupancy/chunk-size/barriers all
// falsified in R5-R7). Also 4x fewer blocks (per-block overhead probe).
// Fragment-order layout: chunk(p,kb) = 64 lanes x 8 bf16; element (row r, kk):
//   p=r/16, lr=r%16, kb=kk/32, lq=(kk%32)/8, j=kk%8
//   offset = ((p*4+kb)*64 + lq*16 + lr)*8 + j      (kk: 0..63=hi, 64..127=lo)

#define KPAD 136     // (fallback kernel) bf16 row stride
#define CSTRIDE 68   // (fallback) fp32 C-tile row stride
#define CS2 128      // main: fp32 C-tile row stride (128x128 tile = 64 KB LDS)

typedef __attribute__((ext_vector_type(8))) short bfrag8;
typedef __attribute__((ext_vector_type(4))) float facc4;
typedef __attribute__((ext_vector_type(4))) float f32x4;

__device__ __forceinline__ unsigned short f2bf(float v) {
  uint32_t u = __float_as_uint(v);
  u += 0x7fffu + ((u >> 16) & 1u);
  return (unsigned short)(u >> 16);
}
__device__ __forceinline__ float bf2f(unsigned short h) {
  return __uint_as_float(((uint32_t)h) << 16);
}

// ---------------- pre-pass: convert + pack in fragment order ----------------
__global__ __launch_bounds__(256)
void qkm_prep(const float* __restrict__ x, const float* __restrict__ y,
              const float* __restrict__ gamma,
              unsigned short* __restrict__ Apack, unsigned short* __restrict__ Bpack,
              float* __restrict__ sqx, float* __restrict__ sqy, int N, int M) {
  const int t = blockIdx.x * blockDim.x + threadIdx.x;
  const bool isB = (t >= N);
  const int r = isB ? (t - N) : t;
  if (isB && r >= M) return;
  const float4* src = (const float4*)((isB ? y : x) + (size_t)r * 64);
  const float4* gv = (const float4*)gamma;
  unsigned short* dst = isB ? Bpack : Apack;

  unsigned short hi[64], lo[64];
  float s = 0.f;
#pragma unroll
  for (int c = 0; c < 16; ++c) {
    const float4 v = src[c];
    const float4 g4 = gv[c];
    const float vj[4] = {v.x, v.y, v.z, v.w};
    const float gj[4] = {g4.x, g4.y, g4.z, g4.w};
#pragma unroll
    for (int j = 0; j < 4; ++j) {
      const float val = vj[j];
      s = fmaf(gj[j] * val, val, s);
      const float wv = isB ? (2.f * gj[j] * val) : val;
      const unsigned short h = f2bf(wv);
      hi[c * 4 + j] = h;
      lo[c * 4 + j] = f2bf(wv - bf2f(h));
    }
  }
  (isB ? sqy : sqx)[r] = s;

  const int p = r >> 4, lr = r & 15;
#pragma unroll
  for (int kb = 0; kb < 4; ++kb) {
#pragma unroll
    for (int lq = 0; lq < 4; ++lq) {
      unsigned short tmp[8];
#pragma unroll
      for (int j = 0; j < 8; ++j) {
        const int kk = kb * 32 + lq * 8 + j;
        tmp[j] = (kk < 64) ? hi[kk] : lo[kk - 64];
      }
      uint4 pk;
      pk.x = (uint32_t)tmp[0] | ((uint32_t)tmp[1] << 16);
      pk.y = (uint32_t)tmp[2] | ((uint32_t)tmp[3] << 16);
      pk.z = (uint32_t)tmp[4] | ((uint32_t)tmp[5] << 16);
      pk.w = (uint32_t)tmp[6] | ((uint32_t)tmp[7] << 16);
      *(uint4*)&dst[(((size_t)(p * 4 + kb)) * 64 + lq * 16 + lr) * 8] = pk;
    }
  }
}

// ---- main: 128x128 tile; wave = private 32x128 row-slab; NO barriers -------
__global__ __launch_bounds__(256, 2)
void qkm_main(const unsigned short* __restrict__ Apack,
              const unsigned short* __restrict__ Bpack,
              const float* __restrict__ sqx, const float* __restrict__ sqy,
              float* __restrict__ out, int M) {
  __shared__ __align__(16) float Ct[128 * CS2];  // exactly 64 KB

  const int tid = threadIdx.x;
  const int l = tid & 63, wv = tid >> 6;
  const int n0 = blockIdx.y * 128, m0 = blockIdx.x * 128;
  const int lr = l & 15, lq = l >> 4;

  // wave's rows: n0 + wv*32 (2 panels); B col-panels 0..7 shared by all waves
  const unsigned short* Af = Apack + (((size_t)((n0 >> 4) + wv * 2) * 4) * 64 + l) * 8;
  const unsigned short* Bf = Bpack + (((size_t)(m0 >> 4) * 4) * 64 + l) * 8;

  // A frags resident: 2 row-panels x {hi,lo} x 2 k-chunks = 32 VGPRs
  bfrag8 aH[2][2], aL[2][2];
#pragma unroll
  for (int rp = 0; rp < 2; ++rp)
#pragma unroll
    for (int k = 0; k < 2; ++k) {
      aH[rp][k] = *(const bfrag8*)(Af + ((size_t)(rp * 4 + k)) * 512);
      aL[rp][k] = *(const bfrag8*)(Af + ((size_t)(rp * 4 + 2 + k)) * 512);
    }

  facc4 acc[2][8] = {};
#pragma unroll
  for (int ct = 0; ct < 8; ++ct) {
    bfrag8 bH[2], bL[2];
#pragma unroll
    for (int k = 0; k < 2; ++k) {
      bH[k] = *(const bfrag8*)(Bf + ((size_t)(ct * 4 + k)) * 512);
      bL[k] = *(const bfrag8*)(Bf + ((size_t)(ct * 4 + 2 + k)) * 512);
    }
#pragma unroll
    for (int k = 0; k < 2; ++k)
#pragma unroll
      for (int rp = 0; rp < 2; ++rp) {
        acc[rp][ct] = __builtin_amdgcn_mfma_f32_16x16x32_bf16(aH[rp][k], bH[k], acc[rp][ct], 0, 0, 0);
        acc[rp][ct] = __builtin_amdgcn_mfma_f32_16x16x32_bf16(aL[rp][k], bH[k], acc[rp][ct], 0, 0, 0);
        acc[rp][ct] = __builtin_amdgcn_mfma_f32_16x16x32_bf16(aH[rp][k], bL[k], acc[rp][ct], 0, 0, 0);
      }
  }

  // epilogue (wave-private, barrier-free): exp -> LDS patch -> rows -> stores
  // C/D layout (16x16): col = l&15, row = (l>>4)*4 + reg
  float* Cw = &Ct[wv * 32 * CS2];
#pragma unroll
  for (int rp = 0; rp < 2; ++rp) {
    const float4 sx = *(const float4*)&sqx[n0 + wv * 32 + rp * 16 + lq * 4];
    const float sxa[4] = {sx.x, sx.y, sx.z, sx.w};
#pragma unroll
    for (int ct = 0; ct < 8; ++ct) {
      const int col = ct * 16 + lr;
      const float sy = sqy[m0 + col];
#pragma unroll
      for (int q = 0; q < 4; ++q)
        Cw[(rp * 16 + lq * 4 + q) * CS2 + col] = __expf(acc[rp][ct][q] - sxa[q] - sy);
    }
  }
  // intra-wave RAW through LDS: lgkmcnt wait only, no s_barrier
#pragma unroll
  for (int i = 0; i < 16; ++i) {
    const int f = l + 64 * i;      // 0..1023 within the wave's 32x128 slab
    const int row = f >> 5;        // 0..31
    const int c4 = f & 31;         // float4 index along 128 cols
    const f32x4 v = *(const f32x4*)(Cw + row * CS2 + c4 * 4);
    __builtin_nontemporal_store(
        v, (f32x4*)(out + (size_t)(n0 + wv * 32 + row) * M + m0 + c4 * 4));
  }
}

// ---------------- fallback (R2 self-contained) if ws too small --------------
__global__ __launch_bounds__(256, 4)
void qkm_rbf_fallback(const float* __restrict__ x, const float* __restrict__ y,
                      const float* __restrict__ gamma, float* __restrict__ out,
                      int M) {
  __shared__ __align__(16) unsigned short Ah[64 * KPAD];
  __shared__ __align__(16) unsigned short Bh[64 * KPAD];
  __shared__ float sqx[64];
  __shared__ float sqy[64];

  const int tid = threadIdx.x;
  const int n0 = blockIdx.y * 64;
  const int m0 = blockIdx.x * 64;
  {
    const float4* xv = (const float4*)(x + (size_t)n0 * 64);
    const float4* yv = (const float4*)(y + (size_t)m0 * 64);
    const float4* gv = (const float4*)gamma;
#pragma unroll
    for (int i = 0; i < 4; ++i) {
      const int f = tid + 256 * i;
      const int r = f >> 4;
      const int c = f & 15;
      const float4 g4 = gv[c];
      const float gj[4] = {g4.x, g4.y, g4.z, g4.w};
      {
        const float4 v = xv[f];
        const float vj[4] = {v.x, v.y, v.z, v.w};
        unsigned short h[4], lo[4];
        float s = 0.f;
#pragma unroll
        for (int j = 0; j < 4; ++j) {
          const float xval = vj[j];
          h[j] = f2bf(xval);
          lo[j] = f2bf(xval - bf2f(h[j]));
          s = fmaf(gj[j] * xval, xval, s);
        }
        uint2 hp, lp;
        hp.x = (uint32_t)h[0] | ((uint32_t)h[1] << 16);
        hp.y = (uint32_t)h[2] | ((uint32_t)h[3] << 16);
        lp.x = (uint32_t)lo[0] | ((uint32_t)lo[1] << 16);
        lp.y = (uint32_t)lo[2] | ((uint32_t)lo[3] << 16);
        *(uint2*)&Ah[r * KPAD + c * 4]      = hp;
        *(uint2*)&Ah[r * KPAD + 64 + c * 4] = lp;
        s += __shfl_xor(s, 1); s += __shfl_xor(s, 2);
        s += __shfl_xor(s, 4); s += __shfl_xor(s, 8);
        if (c == 0) sqx[r] = s;
      }
      {
        const float4 v = yv[f];
        const float vj[4] = {v.x, v.y, v.z, v.w};
        unsigned short h[4], lo[4];
        float s = 0.f;
#pragma unroll
        for (int j = 0; j < 4; ++j) {
          const float yval = vj[j];
          const float w = 2.f * gj[j] * yval;
          h[j] = f2bf(w);
          lo[j] = f2bf(w - bf2f(h[j]));
          s = fmaf(gj[j] * yval, yval, s);
        }
        uint2 hp, lp;
        hp.x = (uint32_t)h[0] | ((uint32_t)h[1] << 16);
        hp.y = (uint32_t)h[2] | ((uint32_t)h[3] << 16);
        lp.x = (uint32_t)lo[0] | ((uint32_t)lo[1] << 16);
        lp.y = (uint32_t)lo[2] | ((uint32_t)lo[3] << 16);
        *(uint2*)&Bh[r * KPAD + c * 4]      = hp;
        *(uint2*)&Bh[r * KPAD + 64 + c * 4] = lp;
        s += __shfl_xor(s, 1); s += __shfl_xor(s, 2);
        s += __shfl_xor(s, 4); s += __shfl_xor(s, 8);
        if (c == 0) sqy[r] = s;
      }
    }
  }
  __syncthreads();

  const int l = tid & 63;
  const int wv = tid >> 6;
  const int rb = (wv & 1) * 32;
  const int cb = (wv >> 1) * 32;
  const int lr = l & 15;
  const int lq = l >> 4;

  facc4 acc[2][2] = {};
  const unsigned short* A0 = &Ah[(rb + lr) * KPAD + lq * 8];
  const unsigned short* A1 = A0 + 16 * KPAD;
  const unsigned short* B0 = &Bh[(cb + lr) * KPAD + lq * 8];
  const unsigned short* B1 = B0 + 16 * KPAD;
  const int akb[6] = {0, 32, 0, 32, 64, 96};
  const int bkb[6] = {0, 32, 64, 96, 0, 32};
#pragma unroll
  for (int p = 0; p < 6; ++p) {
    bfrag8 a0 = *(const bfrag8*)(A0 + akb[p]);
    bfrag8 a1 = *(const bfrag8*)(A1 + akb[p]);
    bfrag8 b0 = *(const bfrag8*)(B0 + bkb[p]);
    bfrag8 b1 = *(const bfrag8*)(B1 + bkb[p]);
    acc[0][0] = __builtin_amdgcn_mfma_f32_16x16x32_bf16(a0, b0, acc[0][0], 0, 0, 0);
    acc[0][1] = __builtin_amdgcn_mfma_f32_16x16x32_bf16(a0, b1, acc[0][1], 0, 0, 0);
    acc[1][0] = __builtin_amdgcn_mfma_f32_16x16x32_bf16(a1, b0, acc[1][0], 0, 0, 0);
    acc[1][1] = __builtin_amdgcn_mfma_f32_16x16x32_bf16(a1, b1, acc[1][1], 0, 0, 0);
  }
  __syncthreads();

  float* Ctf = (float*)Ah;
  const float sy0 = sqy[cb + lr];
  const float sy1 = sqy[cb + 16 + lr];
#pragma unroll
  for (int ti = 0; ti < 2; ++ti) {
    const int rloc = rb + ti * 16 + lq * 4;
    const float4 sx = *(const float4*)&sqx[rloc];
    const float sxa[4] = {sx.x, sx.y, sx.z, sx.w};
#pragma unroll
    for (int q = 0; q < 4; ++q) {
      float* crow = Ctf + (size_t)(rloc + q) * CSTRIDE;
      crow[cb + lr]      = __expf(acc[ti][0][q] - sxa[q] - sy0);
      crow[cb + 16 + lr] = __expf(acc[ti][1][q] - sxa[q] - sy1);
    }
  }
  __syncthreads();
#pragma unroll
  for (int i = 0; i < 4; ++i) {
    const int f = tid + 256 * i;
    const int row = f >> 4;
    const int c4 = f & 15;
    const float4 v = *(const float4*)(Ctf + row * CSTRIDE + c4 * 4);
    *(float4*)(out + (size_t)(n0 + row) * M + m0 + c4 * 4) = v;
  }
}

extern "C" void kernel_launch(void* const* d_in, const int* in_sizes, int n_in,
                              void* d_out, int out_size, void* d_ws, size_t ws_size,
                              hipStream_t stream) {
  const float* x = (const float*)d_in[0];
  const float* y = (const float*)d_in[1];
  const float* g = (const float*)d_in[2];
  float* out = (float*)d_out;
  const int D = in_sizes[2];       // 64
  const int N = in_sizes[0] / D;   // 8192
  const int M = in_sizes[1] / D;   // 8192

  const size_t aBytes = (size_t)N * 128 * sizeof(unsigned short);  // hi|lo packed
  const size_t bBytes = (size_t)M * 128 * sizeof(unsigned short);
  const size_t sxBytes = (size_t)N * sizeof(float);
  const size_t syBytes = (size_t)M * sizeof(float);
  const size_t need = aBytes + bBytes + sxBytes + syBytes + 256;

  if (ws_size >= need) {
    char* ws = (char*)d_ws;
    unsigned short* Apack = (unsigned short*)ws;
    unsigned short* Bpack = (unsigned short*)(ws + aBytes);
    float* sqx = (float*)(ws + aBytes + bBytes);
    float* sqy = (float*)(ws + aBytes + bBytes + sxBytes);
    qkm_prep<<<(N + M + 255) / 256, 256, 0, stream>>>(x, y, g, Apack, Bpack, sqx, sqy, N, M);
    dim3 grid(M / 128, N / 128);
    qkm_main<<<grid, dim3(256), 0, stream>>>(Apack, Bpack, sqx, sqy, out, M);
  } else {
    dim3 grid(M / 64, N / 64);
    qkm_rbf_fallback<<<grid, dim3(256), 0, stream>>>(x, y, g, out, M);
  }
}

// Round 9
// 277.521 us; speedup vs baseline: 1.0294x; 1.0294x over previous
//
#include <hip/hip_runtime.h>
#include <hip/hip_bf16.h>
#include <stdint.h>

// RBF kernel matrix: out[n,m] = exp(2*x.(g*y) - sqx[n] - sqy[m])
// R9 = revert to R4 (session best, 278.50 us): pre-pass converts x and w=2*g*y
// to split-bf16 (hi/lo) once in MFMA fragment order in d_ws; main kernel:
// coalesced frag loads (L2-resident) -> 24 MFMAs -> exp -> LDS transpose ->
// nontemporal float4 stores.
// Falsified levers (R5-R8, all neutral or -2%): occupancy 4->6 blk/CU,
// store chunk 256B->1KB, barrier-free epilogue, L2 reads /2 + 128x128 tile.
// Remaining ~18us over the 42us write floor is intrinsic to the mixed
// read+compute+write stream; bench is ~75% harness poison-fill.
// Fragment-order layout: chunk(p,kb) = 64 lanes x 8 bf16; element (row r, kk):
//   p=r/16, lr=r%16, kb=kk/32, lq=(kk%32)/8, j=kk%8
//   offset = ((p*4+kb)*64 + lq*16 + lr)*8 + j      (kk: 0..63=hi, 64..127=lo)

#define KPAD 136     // (fallback kernel) bf16 row stride
#define CSTRIDE 68   // fp32 C-tile row stride: 64 + 4 pad (2-way conflicts only)

typedef __attribute__((ext_vector_type(8))) short bfrag8;
typedef __attribute__((ext_vector_type(4))) float facc4;
typedef __attribute__((ext_vector_type(4))) float f32x4;

__device__ __forceinline__ unsigned short f2bf(float v) {
  uint32_t u = __float_as_uint(v);
  u += 0x7fffu + ((u >> 16) & 1u);
  return (unsigned short)(u >> 16);
}
__device__ __forceinline__ float bf2f(unsigned short h) {
  return __uint_as_float(((uint32_t)h) << 16);
}

// ---------------- pre-pass: convert + pack in fragment order ----------------
__global__ __launch_bounds__(256)
void qkm_prep(const float* __restrict__ x, const float* __restrict__ y,
              const float* __restrict__ gamma,
              unsigned short* __restrict__ Apack, unsigned short* __restrict__ Bpack,
              float* __restrict__ sqx, float* __restrict__ sqy, int N, int M) {
  const int t = blockIdx.x * blockDim.x + threadIdx.x;
  const bool isB = (t >= N);
  const int r = isB ? (t - N) : t;
  if (isB && r >= M) return;
  const float4* src = (const float4*)((isB ? y : x) + (size_t)r * 64);
  const float4* gv = (const float4*)gamma;
  unsigned short* dst = isB ? Bpack : Apack;

  unsigned short hi[64], lo[64];
  float s = 0.f;
#pragma unroll
  for (int c = 0; c < 16; ++c) {
    const float4 v = src[c];
    const float4 g4 = gv[c];
    const float vj[4] = {v.x, v.y, v.z, v.w};
    const float gj[4] = {g4.x, g4.y, g4.z, g4.w};
#pragma unroll
    for (int j = 0; j < 4; ++j) {
      const float val = vj[j];
      s = fmaf(gj[j] * val, val, s);
      const float wv = isB ? (2.f * gj[j] * val) : val;
      const unsigned short h = f2bf(wv);
      hi[c * 4 + j] = h;
      lo[c * 4 + j] = f2bf(wv - bf2f(h));
    }
  }
  (isB ? sqy : sqx)[r] = s;

  const int p = r >> 4, lr = r & 15;
#pragma unroll
  for (int kb = 0; kb < 4; ++kb) {
#pragma unroll
    for (int lq = 0; lq < 4; ++lq) {
      unsigned short tmp[8];
#pragma unroll
      for (int j = 0; j < 8; ++j) {
        const int kk = kb * 32 + lq * 8 + j;
        tmp[j] = (kk < 64) ? hi[kk] : lo[kk - 64];
      }
      uint4 pk;
      pk.x = (uint32_t)tmp[0] | ((uint32_t)tmp[1] << 16);
      pk.y = (uint32_t)tmp[2] | ((uint32_t)tmp[3] << 16);
      pk.z = (uint32_t)tmp[4] | ((uint32_t)tmp[5] << 16);
      pk.w = (uint32_t)tmp[6] | ((uint32_t)tmp[7] << 16);
      *(uint4*)&dst[(((size_t)(p * 4 + kb)) * 64 + lq * 16 + lr) * 8] = pk;
    }
  }
}

// ---------------- main: frag loads -> MFMA -> exp -> coalesced store --------
__global__ __launch_bounds__(256, 4)
void qkm_main(const unsigned short* __restrict__ Apack,
              const unsigned short* __restrict__ Bpack,
              const float* __restrict__ sqx, const float* __restrict__ sqy,
              float* __restrict__ out, int M) {
  __shared__ __align__(16) float Ct[64 * CSTRIDE];

  const int tid = threadIdx.x;
  const int l = tid & 63, wv = tid >> 6;
  const int n0 = blockIdx.y * 64, m0 = blockIdx.x * 64;
  const int rb = (wv & 1) * 32, cb = (wv >> 1) * 32;
  const int lr = l & 15, lq = l >> 4;

  // chunk(p,kb) base + lane*8 bf16; panel p advances chunk index by 4
  const unsigned short* Af = Apack + (((size_t)((n0 + rb) >> 4) * 4) * 64 + l) * 8;
  const unsigned short* Bf = Bpack + (((size_t)((m0 + cb) >> 4) * 4) * 64 + l) * 8;

  bfrag8 a[2][4], b[2][4];
#pragma unroll
  for (int dp = 0; dp < 2; ++dp)
#pragma unroll
    for (int kb = 0; kb < 4; ++kb) {
      a[dp][kb] = *(const bfrag8*)(Af + (size_t)(dp * 4 + kb) * 512);
      b[dp][kb] = *(const bfrag8*)(Bf + (size_t)(dp * 4 + kb) * 512);
    }

  facc4 acc[2][2] = {};
  // kb pairs: hi*hi (0,0),(1,1); hi*lo (0,2),(1,3); lo*hi (2,0),(3,1)
  const int ka[6] = {0, 1, 0, 1, 2, 3};
  const int kc[6] = {0, 1, 2, 3, 0, 1};
#pragma unroll
  for (int s = 0; s < 6; ++s) {
#pragma unroll
    for (int dp = 0; dp < 2; ++dp)
#pragma unroll
      for (int dq = 0; dq < 2; ++dq)
        acc[dp][dq] = __builtin_amdgcn_mfma_f32_16x16x32_bf16(
            a[dp][ka[s]], b[dq][kc[s]], acc[dp][dq], 0, 0, 0);
  }

  // epilogue part 1: exp(acc - sqx - sqy) -> LDS C tile
  const float sy0 = sqy[m0 + cb + lr];
  const float sy1 = sqy[m0 + cb + 16 + lr];
#pragma unroll
  for (int ti = 0; ti < 2; ++ti) {
    const int rloc = rb + ti * 16 + lq * 4;
    const float4 sx = *(const float4*)&sqx[n0 + rloc];
    const float sxa[4] = {sx.x, sx.y, sx.z, sx.w};
#pragma unroll
    for (int q = 0; q < 4; ++q) {
      float* crow = Ct + (size_t)(rloc + q) * CSTRIDE;
      crow[cb + lr]      = __expf(acc[ti][0][q] - sxa[q] - sy0);
      crow[cb + 16 + lr] = __expf(acc[ti][1][q] - sxa[q] - sy1);
    }
  }
  __syncthreads();

  // epilogue part 2: coalesced nontemporal float4 stores
#pragma unroll
  for (int i = 0; i < 4; ++i) {
    const int f = tid + 256 * i;
    const int row = f >> 4;
    const int c4 = f & 15;
    const f32x4 v = *(const f32x4*)(Ct + row * CSTRIDE + c4 * 4);
    __builtin_nontemporal_store(v, (f32x4*)(out + (size_t)(n0 + row) * M + m0 + c4 * 4));
  }
}

// ---------------- fallback (R2 self-contained) if ws too small --------------
__global__ __launch_bounds__(256, 4)
void qkm_rbf_fallback(const float* __restrict__ x, const float* __restrict__ y,
                      const float* __restrict__ gamma, float* __restrict__ out,
                      int M) {
  __shared__ __align__(16) unsigned short Ah[64 * KPAD];
  __shared__ __align__(16) unsigned short Bh[64 * KPAD];
  __shared__ float sqx[64];
  __shared__ float sqy[64];

  const int tid = threadIdx.x;
  const int n0 = blockIdx.y * 64;
  const int m0 = blockIdx.x * 64;
  {
    const float4* xv = (const float4*)(x + (size_t)n0 * 64);
    const float4* yv = (const float4*)(y + (size_t)m0 * 64);
    const float4* gv = (const float4*)gamma;
#pragma unroll
    for (int i = 0; i < 4; ++i) {
      const int f = tid + 256 * i;
      const int r = f >> 4;
      const int c = f & 15;
      const float4 g4 = gv[c];
      const float gj[4] = {g4.x, g4.y, g4.z, g4.w};
      {
        const float4 v = xv[f];
        const float vj[4] = {v.x, v.y, v.z, v.w};
        unsigned short h[4], lo[4];
        float s = 0.f;
#pragma unroll
        for (int j = 0; j < 4; ++j) {
          const float xval = vj[j];
          h[j] = f2bf(xval);
          lo[j] = f2bf(xval - bf2f(h[j]));
          s = fmaf(gj[j] * xval, xval, s);
        }
        uint2 hp, lp;
        hp.x = (uint32_t)h[0] | ((uint32_t)h[1] << 16);
        hp.y = (uint32_t)h[2] | ((uint32_t)h[3] << 16);
        lp.x = (uint32_t)lo[0] | ((uint32_t)lo[1] << 16);
        lp.y = (uint32_t)lo[2] | ((uint32_t)lo[3] << 16);
        *(uint2*)&Ah[r * KPAD + c * 4]      = hp;
        *(uint2*)&Ah[r * KPAD + 64 + c * 4] = lp;
        s += __shfl_xor(s, 1); s += __shfl_xor(s, 2);
        s += __shfl_xor(s, 4); s += __shfl_xor(s, 8);
        if (c == 0) sqx[r] = s;
      }
      {
        const float4 v = yv[f];
        const float vj[4] = {v.x, v.y, v.z, v.w};
        unsigned short h[4], lo[4];
        float s = 0.f;
#pragma unroll
        for (int j = 0; j < 4; ++j) {
          const float yval = vj[j];
          const float w = 2.f * gj[j] * yval;
          h[j] = f2bf(w);
          lo[j] = f2bf(w - bf2f(h[j]));
          s = fmaf(gj[j] * yval, yval, s);
        }
        uint2 hp, lp;
        hp.x = (uint32_t)h[0] | ((uint32_t)h[1] << 16);
        hp.y = (uint32_t)h[2] | ((uint32_t)h[3] << 16);
        lp.x = (uint32_t)lo[0] | ((uint32_t)lo[1] << 16);
        lp.y = (uint32_t)lo[2] | ((uint32_t)lo[3] << 16);
        *(uint2*)&Bh[r * KPAD + c * 4]      = hp;
        *(uint2*)&Bh[r * KPAD + 64 + c * 4] = lp;
        s += __shfl_xor(s, 1); s += __shfl_xor(s, 2);
        s += __shfl_xor(s, 4); s += __shfl_xor(s, 8);
        if (c == 0) sqy[r] = s;
      }
    }
  }
  __syncthreads();

  const int l = tid & 63;
  const int wv = tid >> 6;
  const int rb = (wv & 1) * 32;
  const int cb = (wv >> 1) * 32;
  const int lr = l & 15;
  const int lq = l >> 4;

  facc4 acc[2][2] = {};
  const unsigned short* A0 = &Ah[(rb + lr) * KPAD + lq * 8];
  const unsigned short* A1 = A0 + 16 * KPAD;
  const unsigned short* B0 = &Bh[(cb + lr) * KPAD + lq * 8];
  const unsigned short* B1 = B0 + 16 * KPAD;
  const int akb[6] = {0, 32, 0, 32, 64, 96};
  const int bkb[6] = {0, 32, 64, 96, 0, 32};
#pragma unroll
  for (int p = 0; p < 6; ++p) {
    bfrag8 a0 = *(const bfrag8*)(A0 + akb[p]);
    bfrag8 a1 = *(const bfrag8*)(A1 + akb[p]);
    bfrag8 b0 = *(const bfrag8*)(B0 + bkb[p]);
    bfrag8 b1 = *(const bfrag8*)(B1 + bkb[p]);
    acc[0][0] = __builtin_amdgcn_mfma_f32_16x16x32_bf16(a0, b0, acc[0][0], 0, 0, 0);
    acc[0][1] = __builtin_amdgcn_mfma_f32_16x16x32_bf16(a0, b1, acc[0][1], 0, 0, 0);
    acc[1][0] = __builtin_amdgcn_mfma_f32_16x16x32_bf16(a1, b0, acc[1][0], 0, 0, 0);
    acc[1][1] = __builtin_amdgcn_mfma_f32_16x16x32_bf16(a1, b1, acc[1][1], 0, 0, 0);
  }
  __syncthreads();

  float* Ctf = (float*)Ah;
  const float sy0 = sqy[cb + lr];
  const float sy1 = sqy[cb + 16 + lr];
#pragma unroll
  for (int ti = 0; ti < 2; ++ti) {
    const int rloc = rb + ti * 16 + lq * 4;
    const float4 sx = *(const float4*)&sqx[rloc];
    const float sxa[4] = {sx.x, sx.y, sx.z, sx.w};
#pragma unroll
    for (int q = 0; q < 4; ++q) {
      float* crow = Ctf + (size_t)(rloc + q) * CSTRIDE;
      crow[cb + lr]      = __expf(acc[ti][0][q] - sxa[q] - sy0);
      crow[cb + 16 + lr] = __expf(acc[ti][1][q] - sxa[q] - sy1);
    }
  }
  __syncthreads();
#pragma unroll
  for (int i = 0; i < 4; ++i) {
    const int f = tid + 256 * i;
    const int row = f >> 4;
    const int c4 = f & 15;
    const float4 v = *(const float4*)(Ctf + row * CSTRIDE + c4 * 4);
    *(float4*)(out + (size_t)(n0 + row) * M + m0 + c4 * 4) = v;
  }
}

extern "C" void kernel_launch(void* const* d_in, const int* in_sizes, int n_in,
                              void* d_out, int out_size, void* d_ws, size_t ws_size,
                              hipStream_t stream) {
  const float* x = (const float*)d_in[0];
  const float* y = (const float*)d_in[1];
  const float* g = (const float*)d_in[2];
  float* out = (float*)d_out;
  const int D = in_sizes[2];       // 64
  const int N = in_sizes[0] / D;   // 8192
  const int M = in_sizes[1] / D;   // 8192

  const size_t aBytes = (size_t)N * 128 * sizeof(unsigned short);  // hi|lo packed
  const size_t bBytes = (size_t)M * 128 * sizeof(unsigned short);
  const size_t sxBytes = (size_t)N * sizeof(float);
  const size_t syBytes = (size_t)M * sizeof(float);
  const size_t need = aBytes + bBytes + sxBytes + syBytes + 256;

  if (ws_size >= need) {
    char* ws = (char*)d_ws;
    unsigned short* Apack = (unsigned short*)ws;
    unsigned short* Bpack = (unsigned short*)(ws + aBytes);
    float* sqx = (float*)(ws + aBytes + bBytes);
    float* sqy = (float*)(ws + aBytes + bBytes + sxBytes);
    qkm_prep<<<(N + M + 255) / 256, 256, 0, stream>>>(x, y, g, Apack, Bpack, sqx, sqy, N, M);
    dim3 grid(M / 64, N / 64);
    qkm_main<<<grid, dim3(256), 0, stream>>>(Apack, Bpack, sqx, sqy, out, M);
  } else {
    dim3 grid(M / 64, N / 64);
    qkm_rbf_fallback<<<grid, dim3(256), 0, stream>>>(x, y, g, out, M);
  }
}